// Round 7
// baseline (263.772 us; speedup 1.0000x reference)
//
#include <hip/hip_runtime.h>
#include <hip/hip_bf16.h>

// Problem constants (from reference)
#define DIMX   768
#define HEADS  12
#define DH     64
#define INNER  768
#define NQKV   2304
#define SEQ    4096
#define BATCH  2
#define ROWS   (BATCH*SEQ)   // 8192
#define EPSF   1e-8f
#define LOG2E  1.4426950408889634f

typedef __bf16 bf16x8 __attribute__((ext_vector_type(8)));
typedef float  f32x4  __attribute__((ext_vector_type(4)));
typedef float  f32x16 __attribute__((ext_vector_type(16)));

// RNE f32 -> bf16 (finite inputs only)
__device__ __forceinline__ unsigned short f2bf(float f) {
    unsigned int u = __float_as_uint(f);
    unsigned int r = ((u >> 16) & 1u) + 0x7FFFu;
    return (unsigned short)((u + r) >> 16);
}
__device__ __forceinline__ float bf2f(unsigned short u) {
    return __builtin_bit_cast(float, (unsigned)u << 16);
}
// pack two f32 into a u32 of 2 bf16 (lo = a, hi = b) via native casts
__device__ __forceinline__ unsigned pkbf(float a, float b) {
    unsigned short la = __builtin_bit_cast(unsigned short, (__bf16)a);
    unsigned short lb = __builtin_bit_cast(unsigned short, (__bf16)b);
    return (unsigned)la | ((unsigned)lb << 16);
}

__global__ __launch_bounds__(256) void cast_f32_bf16(
    const float* __restrict__ src, unsigned short* __restrict__ dst, int n)
{
    int i = (blockIdx.x * 256 + threadIdx.x) * 4;
    if (i + 3 < n) {
        float4 v = *reinterpret_cast<const float4*>(src + i);
        ushort4 o;
        o.x = f2bf(v.x); o.y = f2bf(v.y); o.z = f2bf(v.z); o.w = f2bf(v.w);
        *reinterpret_cast<ushort4*>(dst + i) = o;
    }
}

// C[M][N] = A[M][K] (bf16) * B[N][K]^T (bf16) (+ bias); out f32 or bf16.
template<bool BF16OUT>
__global__ __launch_bounds__(256) void gemm_bt_kernel(
    const unsigned short* __restrict__ A,
    const unsigned short* __restrict__ B,
    void* __restrict__ Cv,
    const float* __restrict__ bias,
    int M, int N, int K)
{
    __shared__ unsigned short shA[128][72];
    __shared__ unsigned short shB[128][72];

    const int bm0 = blockIdx.x * 128;
    const int bn0 = blockIdx.y * 128;
    const int tid = threadIdx.x;
    const int lane = tid & 63;
    const int wid  = tid >> 6;
    const int l15  = lane & 15;
    const int l4   = lane >> 4;
    const int wr   = wid >> 1;
    const int wc   = wid & 1;

    f32x4 acc[4][4];
    #pragma unroll
    for (int i = 0; i < 4; ++i)
        #pragma unroll
        for (int j = 0; j < 4; ++j)
            acc[i][j] = (f32x4){0.f, 0.f, 0.f, 0.f};

    const int nkt = K >> 6;
    for (int kt = 0; kt < nkt; ++kt) {
        const int k0 = kt << 6;
        __syncthreads();
        #pragma unroll
        for (int it = 0; it < 4; ++it) {
            int c = tid + it * 256;
            int row = c >> 3, colc = c & 7;
            *reinterpret_cast<uint4*>(&shA[row][colc * 8]) =
                *reinterpret_cast<const uint4*>(&A[(size_t)(bm0 + row) * K + k0 + colc * 8]);
            *reinterpret_cast<uint4*>(&shB[row][colc * 8]) =
                *reinterpret_cast<const uint4*>(&B[(size_t)(bn0 + row) * K + k0 + colc * 8]);
        }
        __syncthreads();
        #pragma unroll
        for (int ks = 0; ks < 2; ++ks) {
            bf16x8 af[4], bfr[4];
            #pragma unroll
            for (int mf = 0; mf < 4; ++mf)
                af[mf] = *reinterpret_cast<const bf16x8*>(&shA[wr * 64 + mf * 16 + l15][ks * 32 + l4 * 8]);
            #pragma unroll
            for (int nf = 0; nf < 4; ++nf)
                bfr[nf] = *reinterpret_cast<const bf16x8*>(&shB[wc * 64 + nf * 16 + l15][ks * 32 + l4 * 8]);
            #pragma unroll
            for (int mf = 0; mf < 4; ++mf)
                #pragma unroll
                for (int nf = 0; nf < 4; ++nf)
                    acc[mf][nf] = __builtin_amdgcn_mfma_f32_16x16x32_bf16(
                        af[mf], bfr[nf], acc[mf][nf], 0, 0, 0);
        }
    }

    #pragma unroll
    for (int mf = 0; mf < 4; ++mf) {
        #pragma unroll
        for (int nf = 0; nf < 4; ++nf) {
            int col = bn0 + wc * 64 + nf * 16 + l15;
            float badd = bias ? bias[col] : 0.f;
            #pragma unroll
            for (int r = 0; r < 4; ++r) {
                int row = bm0 + wr * 64 + mf * 16 + l4 * 4 + r;
                if constexpr (BF16OUT)
                    ((unsigned short*)Cv)[(size_t)row * N + col] = f2bf(acc[mf][nf][r] + badd);
                else
                    ((float*)Cv)[(size_t)row * N + col] = acc[mf][nf][r] + badd;
            }
        }
    }
}

// Cross-head L2 norm on bf16 qkv; Q scaled by log2e/scale[h]. q,k only.
__global__ __launch_bounds__(256) void normalize_kernel(
    const unsigned short* __restrict__ qkv,
    const float* __restrict__ scale,
    unsigned short* __restrict__ qo,
    unsigned short* __restrict__ ko)
{
    int t = blockIdx.x * 256 + threadIdx.x;
    int row = t >> 6;
    int d = t & 63;
    int b = row >> 12;
    int n = row & 4095;
    const unsigned short* base = qkv + (size_t)row * NQKV;

    float qv[12], kv[12];
    float sq = 0.f, sk = 0.f;
    #pragma unroll
    for (int h = 0; h < 12; ++h) {
        qv[h] = bf2f(base[h * 64 + d]);
        kv[h] = bf2f(base[768 + h * 64 + d]);
        sq += qv[h] * qv[h];
        sk += kv[h] * kv[h];
    }
    float rq = rsqrtf(sqrtf(sq) + EPSF);
    float rk = rsqrtf(sqrtf(sk) + EPSF);
    #pragma unroll
    for (int h = 0; h < 12; ++h) {
        size_t bh = (size_t)(b * 12 + h);
        float fold = LOG2E / scale[h];
        qo[(bh * SEQ + n) * 64 + d] = f2bf(qv[h] * rq * fold);
        ko[(bh * SEQ + n) * 64 + d] = f2bf(kv[h] * rk);
    }
}

// V transpose: qkv bf16 v-part [b,n,h,d] -> vt [bh][d][n], coalesced both ways
// via a 64x64 LDS tile. Grid: (BATCH*HEADS, SEQ/64).
__global__ __launch_bounds__(256) void vtrans_kernel(
    const unsigned short* __restrict__ qkv,
    unsigned short* __restrict__ vt)
{
    __shared__ unsigned short tile[64][72];
    const int bh = blockIdx.x;
    const int nt = blockIdx.y;
    const int b = bh / HEADS, h = bh % HEADS;
    const int tid = threadIdx.x;

    #pragma unroll
    for (int it = 0; it < 2; ++it) {
        int c = tid + it * 256;
        int r = c >> 3, cc = c & 7;
        *reinterpret_cast<uint4*>(&tile[r][cc * 8]) =
            *reinterpret_cast<const uint4*>(
                &qkv[(size_t)(b * SEQ + nt * 64 + r) * NQKV + 1536 + h * 64 + cc * 8]);
    }
    __syncthreads();
    #pragma unroll
    for (int it = 0; it < 2; ++it) {
        int c = tid + it * 256;
        int d = c >> 3, nc = c & 7;
        ushort4 o0, o1;
        o0.x = tile[nc * 8 + 0][d]; o0.y = tile[nc * 8 + 1][d];
        o0.z = tile[nc * 8 + 2][d]; o0.w = tile[nc * 8 + 3][d];
        o1.x = tile[nc * 8 + 4][d]; o1.y = tile[nc * 8 + 5][d];
        o1.z = tile[nc * 8 + 6][d]; o1.w = tile[nc * 8 + 7][d];
        unsigned short* dst = &vt[((size_t)bh * 64 + d) * SEQ + nt * 64 + nc * 8];
        *reinterpret_cast<ushort4*>(dst)     = o0;
        *reinterpret_cast<ushort4*>(dst + 4) = o1;
    }
}

// Flash attention, no-max softmax (scores bounded after scale/log2e fold),
// grid-split over KV (blockIdx.z in {0,1}): partials are LINEAR (no max-merge)
// so each split writes raw O^T (f32) and l (f32); combine kernel adds + divides.
// 4 waves / 256 threads; q = lane&31 lane-local throughout.
__global__ __launch_bounds__(256) void attn_kernel(
    const unsigned short* __restrict__ qg,
    const unsigned short* __restrict__ kg,
    const unsigned short* __restrict__ vtg,
    float* __restrict__ po,     // [2][24][SEQ][64]
    float* __restrict__ pl)     // [2][24][SEQ]
{
    __shared__ unsigned short shK[64][72];   // [kv][d]
    __shared__ unsigned short shV[64][72];   // [d][kv]  (V^T)

    const int qblk = blockIdx.x;
    const int bh   = blockIdx.y;
    const int g    = blockIdx.z;
    const int tid  = threadIdx.x;
    const int lane = tid & 63;
    const int wid  = tid >> 6;
    const int l31  = lane & 31;
    const int hi   = lane >> 5;

    // Q fragments (B operand, col=q=l31, k = d0*16 + hi*8 + j)
    bf16x8 qf[4];
    {
        const unsigned short* qrow =
            qg + ((size_t)bh * SEQ + qblk * 128 + wid * 32 + l31) * 64 + hi * 8;
        #pragma unroll
        for (int d0 = 0; d0 < 4; ++d0)
            qf[d0] = *reinterpret_cast<const bf16x8*>(qrow + d0 * 16);
    }

    f32x16 ot[2];
    #pragma unroll
    for (int r = 0; r < 16; ++r) { ot[0][r] = 0.f; ot[1][r] = 0.f; }
    float l_lane = 0.f;

    const unsigned short* kbase = kg  + ((size_t)bh * SEQ + g * 2048) * 64;
    const unsigned short* vbase = vtg + (size_t)bh * 64 * SEQ + g * 2048;

    for (int kt = 0; kt < 32; ++kt) {
        __syncthreads();
        #pragma unroll
        for (int it = 0; it < 2; ++it) {
            int c = tid + it * 256;
            int row = c >> 3, colc = c & 7;
            *reinterpret_cast<uint4*>(&shK[row][colc * 8]) =
                *reinterpret_cast<const uint4*>(&kbase[(size_t)(kt * 64 + row) * 64 + colc * 8]);
            *reinterpret_cast<uint4*>(&shV[row][colc * 8]) =
                *reinterpret_cast<const uint4*>(&vbase[(size_t)row * SEQ + kt * 64 + colc * 8]);
        }
        __syncthreads();

        // ---- S^T = K * Q^T (exp2 domain: scale folded into Q) ----
        f32x16 st0, st1;
        #pragma unroll
        for (int r = 0; r < 16; ++r) { st0[r] = 0.f; st1[r] = 0.f; }
        #pragma unroll
        for (int d0 = 0; d0 < 4; ++d0) {
            bf16x8 kf0 = *reinterpret_cast<const bf16x8*>(&shK[l31][d0 * 16 + hi * 8]);
            bf16x8 kf1 = *reinterpret_cast<const bf16x8*>(&shK[32 + l31][d0 * 16 + hi * 8]);
            st0 = __builtin_amdgcn_mfma_f32_32x32x16_bf16(kf0, qf[d0], st0, 0, 0, 0);
            st1 = __builtin_amdgcn_mfma_f32_32x32x16_bf16(kf1, qf[d0], st1, 0, 0, 0);
        }

        // ---- P = exp2(S), no max shift (scores bounded); pack bf16 pairs ----
        float s0 = 0.f, s1 = 0.f, s2 = 0.f, s3 = 0.f;
        unsigned cp0[8], cp1[8];
        #pragma unroll
        for (int t = 0; t < 8; ++t) {
            float pa = __builtin_amdgcn_exp2f(st0[2 * t]);
            float pb = __builtin_amdgcn_exp2f(st0[2 * t + 1]);
            float pc = __builtin_amdgcn_exp2f(st1[2 * t]);
            float pd = __builtin_amdgcn_exp2f(st1[2 * t + 1]);
            s0 += pa; s1 += pb; s2 += pc; s3 += pd;
            cp0[t] = pkbf(pa, pb);
            cp1[t] = pkbf(pc, pd);
        }
        l_lane += (s0 + s1) + (s2 + s3);

        // ---- O^T += V^T * P^T (cross-half exchange via shfl_xor + select) ----
        #pragma unroll
        for (int cb = 0; cb < 2; ++cb) {
            #pragma unroll
            for (int kk = 0; kk < 2; ++kk) {
                unsigned c0 = cb ? cp1[4 * kk + 0] : cp0[4 * kk + 0];
                unsigned c1 = cb ? cp1[4 * kk + 1] : cp0[4 * kk + 1];
                unsigned c2 = cb ? cp1[4 * kk + 2] : cp0[4 * kk + 2];
                unsigned c3 = cb ? cp1[4 * kk + 3] : cp0[4 * kk + 3];
                unsigned e0 = __shfl_xor(c0, 32);
                unsigned e1 = __shfl_xor(c1, 32);
                unsigned e2 = __shfl_xor(c2, 32);
                unsigned e3 = __shfl_xor(c3, 32);
                union { unsigned uu[4]; bf16x8 v; } pu;
                pu.uu[0] = hi ? e2 : c0;
                pu.uu[1] = hi ? e3 : c1;
                pu.uu[2] = hi ? c2 : e0;
                pu.uu[3] = hi ? c3 : e1;
                #pragma unroll
                for (int df = 0; df < 2; ++df) {
                    bf16x8 vf = *reinterpret_cast<const bf16x8*>(
                        &shV[df * 32 + l31][cb * 32 + kk * 16 + hi * 8]);
                    ot[df] = __builtin_amdgcn_mfma_f32_32x32x16_bf16(vf, pu.v, ot[df], 0, 0, 0);
                }
            }
        }
    }

    // ---- epilogue: write raw partial O^T (f32) and l ----
    float l_all = l_lane + __shfl_xor(l_lane, 32);
    int n = qblk * 128 + wid * 32 + l31;
    float* prow = po + ((size_t)(g * 24 + bh) * SEQ + n) * 64;
    #pragma unroll
    for (int df = 0; df < 2; ++df) {
        #pragma unroll
        for (int t = 0; t < 4; ++t) {
            float4 v = make_float4(ot[df][4 * t], ot[df][4 * t + 1],
                                   ot[df][4 * t + 2], ot[df][4 * t + 3]);
            *reinterpret_cast<float4*>(prow + df * 32 + t * 8 + hi * 4) = v;
        }
    }
    if (hi == 0)
        pl[(size_t)(g * 24 + bh) * SEQ + n] = l_all;
}

// Combine: attnb[(b,n), h*64+d] = (po0 + po1) / (pl0 + pl1), bf16 out.
__global__ __launch_bounds__(256) void combine_kernel(
    const float* __restrict__ po,
    const float* __restrict__ pl,
    unsigned short* __restrict__ attnout)
{
    int idx = blockIdx.x * 256 + threadIdx.x;   // 24*4096*8 threads
    int oct = idx & 7;
    int q   = (idx >> 3) & 4095;
    int bh  = idx >> 15;
    int b = bh / HEADS, h = bh % HEADS;
    int d0 = oct * 8;

    size_t base = ((size_t)bh * SEQ + q) * 64 + d0;
    const float* p0 = po + base;
    const float* p1 = po + (size_t)24 * SEQ * 64 + base;
    float4 a0 = *reinterpret_cast<const float4*>(p0);
    float4 a1 = *reinterpret_cast<const float4*>(p0 + 4);
    float4 b0 = *reinterpret_cast<const float4*>(p1);
    float4 b1 = *reinterpret_cast<const float4*>(p1 + 4);
    float l = pl[(size_t)bh * SEQ + q] + pl[(size_t)24 * SEQ + bh * SEQ + q];
    float inv = 1.0f / l;

    unsigned w0 = pkbf((a0.x + b0.x) * inv, (a0.y + b0.y) * inv);
    unsigned w1 = pkbf((a0.z + b0.z) * inv, (a0.w + b0.w) * inv);
    unsigned w2 = pkbf((a1.x + b1.x) * inv, (a1.y + b1.y) * inv);
    unsigned w3 = pkbf((a1.z + b1.z) * inv, (a1.w + b1.w) * inv);
    uint4 ov = make_uint4(w0, w1, w2, w3);
    *reinterpret_cast<uint4*>(&attnout[((size_t)(b * SEQ + q)) * INNER + h * 64 + d0]) = ov;
}

extern "C" void kernel_launch(void* const* d_in, const int* in_sizes, int n_in,
                              void* d_out, int out_size, void* d_ws, size_t ws_size,
                              hipStream_t stream)
{
    const float* x      = (const float*)d_in[0];
    const float* w_qkv  = (const float*)d_in[1];
    const float* w_out  = (const float*)d_in[2];
    const float* b_out  = (const float*)d_in[3];
    const float* scale  = (const float*)d_in[4];
    float* out = (float*)d_out;
    char* ws = (char*)d_ws;

    unsigned short* xb    = (unsigned short*)(ws);                 // 12,582,912
    unsigned short* wqkvb = (unsigned short*)(ws + 12582912);      //  3,538,944
    unsigned short* woutb = (unsigned short*)(ws + 16121856);      //  1,179,648
    unsigned short* attnb = (unsigned short*)(ws + 17301504);      // 12,582,912
    unsigned short* qb    = (unsigned short*)(ws + 29884416);      // 12,582,912
    unsigned short* kb    = (unsigned short*)(ws + 42467328);      // 12,582,912
    unsigned short* vtb   = (unsigned short*)(ws + 55050240);      // 12,582,912
    unsigned short* qkvb  = (unsigned short*)(ws + 67633152);      // 37,748,736 (dead after vtrans)
    float*          po    = (float*)(ws + 67633152);               // 50,331,648 (overlays qkvb)
    float*          pl    = (float*)(ws + 117964800);              //    786,432
    // peak ws use: 118,751,232 B (< 143 MB proven in round 1)

    cast_f32_bf16<<<6144, 256, 0, stream>>>(x, xb, 6291456);
    cast_f32_bf16<<<1728, 256, 0, stream>>>(w_qkv, wqkvb, 1769472);
    cast_f32_bf16<<<576, 256, 0, stream>>>(w_out, woutb, 589824);

    gemm_bt_kernel<true><<<dim3(64, 18), 256, 0, stream>>>(xb, wqkvb, qkvb, nullptr, ROWS, NQKV, DIMX);

    normalize_kernel<<<2048, 256, 0, stream>>>(qkvb, scale, qb, kb);
    vtrans_kernel<<<dim3(BATCH * HEADS, SEQ / 64), 256, 0, stream>>>(qkvb, vtb);

    attn_kernel<<<dim3(SEQ / 128, BATCH * HEADS, 2), 256, 0, stream>>>(qb, kb, vtb, po, pl);
    combine_kernel<<<3072, 256, 0, stream>>>(po, pl, attnb);

    gemm_bt_kernel<false><<<dim3(64, 6), 256, 0, stream>>>(attnb, woutb, out, b_out, ROWS, INNER, INNER);
}